// Round 1
// 502.096 us; speedup vs baseline: 1.0815x; 1.0815x over previous
//
#include <hip/hip_runtime.h>

#define NDIM  3
#define NCOL  2000
#define RANK  64
#define K1    64
#define NSAMP 8192
constexpr float LAMBD = 0.01f;

#define SPB   4                    // samples per block
#define NBLK  (NSAMP / SPB)        // 2048 blocks, 8 per CU exactly

typedef float f32x4 __attribute__((ext_vector_type(4)));

__global__ void zero_out_kernel(float* out) {
    if (threadIdx.x == 0 && blockIdx.x == 0) out[0] = 0.0f;
}

// 256 threads/block, SPB samples per block.
// Thread t: r-quad = 4*(t&15), k-group = t>>4; eps float4 idx = iter*256 + t (coalesced).
// No LDS staging, no barrier before the streaming loads: means/chols are gathered
// directly as float4 (L2-resident tables, 16-way wave-level broadcast).
template <bool USE_WS>
__global__ __launch_bounds__(256) void ssvi_main(
    const int*   __restrict__ entries,  // [NSAMP, 3]
    const float* __restrict__ ys,       // [NSAMP]
    const float* __restrict__ eps,      // [3, NSAMP, K1, RANK]
    const float* __restrict__ means,    // [3, NCOL, RANK]
    const float* __restrict__ chols,    // [3, NCOL, RANK]
    float*       __restrict__ partial,  // [NBLK] (ws path)
    float*       __restrict__ out)      // scalar (atomic fallback path)
{
    const int t  = threadIdx.x;
    const int r4 = (t & 15) * 4;
    const size_t chunk = (size_t)K1 * RANK;   // 4096 floats per (d, n)

    float acc = 0.0f;

    #pragma unroll 1
    for (int i = 0; i < SPB; ++i) {
        const int n = blockIdx.x * SPB + i;

        // eps pointers depend only on n -> these loads issue without waiting on the gather
        const f32x4* e0p = (const f32x4*)(eps + ((size_t)0 * NSAMP + n) * chunk);
        const f32x4* e1p = (const f32x4*)(eps + ((size_t)1 * NSAMP + n) * chunk);
        const f32x4* e2p = (const f32x4*)(eps + ((size_t)2 * NSAMP + n) * chunk);

        const int c0 = entries[n * NDIM + 0];
        const int c1 = entries[n * NDIM + 1];
        const int c2 = entries[n * NDIM + 2];

        const f32x4 m0 = *(const f32x4*)(means + ((size_t)0 * NCOL + c0) * RANK + r4);
        const f32x4 m1 = *(const f32x4*)(means + ((size_t)1 * NCOL + c1) * RANK + r4);
        const f32x4 m2 = *(const f32x4*)(means + ((size_t)2 * NCOL + c2) * RANK + r4);
        const f32x4 v0 = *(const f32x4*)(chols + ((size_t)0 * NCOL + c0) * RANK + r4);
        const f32x4 v1 = *(const f32x4*)(chols + ((size_t)1 * NCOL + c1) * RANK + r4);
        const f32x4 v2 = *(const f32x4*)(chols + ((size_t)2 * NCOL + c2) * RANK + r4);
        const f32x4 l0 = v0 * v0;   // S = L^2
        const f32x4 l1 = v1 * v1;
        const f32x4 l2 = v2 * v2;

        const float yn = ys[n];

        float pdf_acc = 0.0f;
        #pragma unroll
        for (int iter = 0; iter < 4; ++iter) {
            const int idx = iter * 256 + t;
            const f32x4 e0 = __builtin_nontemporal_load(e0p + idx);
            const f32x4 e1 = __builtin_nontemporal_load(e1p + idx);
            const f32x4 e2 = __builtin_nontemporal_load(e2p + idx);

            const f32x4 f = (m0 + e0 * l0) * (m1 + e1 * l1) * (m2 + e2 * l2);
            float part = (f[0] + f[1]) + (f[2] + f[3]);

            // reduce fs[n,k] over the 16 lanes sharing this k
            #pragma unroll
            for (int off = 8; off > 0; off >>= 1)
                part += __shfl_xor(part, off, 64);

            if ((t & 15) == 0) {
                const float d = part - yn;
                pdf_acc += d * d;
            }
        }
        acc += pdf_acc * (0.5f / (float)K1);

        // KL: threads 0..47 cover (d = t>>4, r-quad) exactly once, from own registers
        if (t < 48) {
            const int d = t >> 4;
            const f32x4 mm = (d == 0) ? m0 : (d == 1) ? m1 : m2;
            const f32x4 ll = (d == 0) ? l0 : (d == 1) ? l1 : l2;
            float klp = 0.0f;
            #pragma unroll
            for (int j = 0; j < 4; ++j)
                klp += 1.0f + 2.0f * __logf(ll[j]) - mm[j] * mm[j] - ll[j] * ll[j];
            acc += klp * (0.5f * LAMBD);
        }
    }

    // wave reduce then block reduce; one store (or atomic) per block
    #pragma unroll
    for (int off = 32; off > 0; off >>= 1)
        acc += __shfl_xor(acc, off, 64);
    __shared__ float wsum[4];
    if ((t & 63) == 0) wsum[t >> 6] = acc;
    __syncthreads();
    if (t == 0) {
        const float s = (wsum[0] + wsum[1]) + (wsum[2] + wsum[3]);
        if constexpr (USE_WS) partial[blockIdx.x] = s;
        else                  atomicAdd(out, s);
    }
}

__global__ __launch_bounds__(256) void ssvi_reduce(
    const float* __restrict__ partial, float* __restrict__ out)
{
    const int t = threadIdx.x;
    float v = 0.0f;
    #pragma unroll
    for (int i = 0; i < NBLK / 256; ++i)
        v += partial[i * 256 + t];
    #pragma unroll
    for (int off = 32; off > 0; off >>= 1)
        v += __shfl_xor(v, off, 64);
    __shared__ float wsum[4];
    if ((t & 63) == 0) wsum[t >> 6] = v;
    __syncthreads();
    if (t == 0) out[0] = (wsum[0] + wsum[1]) + (wsum[2] + wsum[3]);
}

extern "C" void kernel_launch(void* const* d_in, const int* in_sizes, int n_in,
                              void* d_out, int out_size, void* d_ws, size_t ws_size,
                              hipStream_t stream) {
    const int*   entries = (const int*)  d_in[0];
    const float* ys      = (const float*)d_in[1];
    const float* eps     = (const float*)d_in[2];
    const float* means   = (const float*)d_in[3];
    const float* chols   = (const float*)d_in[4];
    float* out = (float*)d_out;

    if (d_ws != nullptr && ws_size >= NBLK * sizeof(float)) {
        float* partial = (float*)d_ws;
        ssvi_main<true><<<NBLK, 256, 0, stream>>>(entries, ys, eps, means, chols, partial, out);
        ssvi_reduce<<<1, 256, 0, stream>>>(partial, out);
    } else {
        zero_out_kernel<<<1, 64, 0, stream>>>(out);
        ssvi_main<false><<<NBLK, 256, 0, stream>>>(entries, ys, eps, means, chols, nullptr, out);
    }
}

// Round 2
// 496.777 us; speedup vs baseline: 1.0931x; 1.0107x over previous
//
#include <hip/hip_runtime.h>

#define NDIM  3
#define NCOL  2000
#define RANK  64
#define K1    64
#define NSAMP 8192
constexpr float LAMBD = 0.01f;

#define SPB   2                    // samples per block
#define NBLK  (NSAMP / SPB)        // 4096 blocks

typedef float f32x4 __attribute__((ext_vector_type(4)));

__global__ void zero_out_kernel(float* out) {
    if (threadIdx.x == 0 && blockIdx.x == 0) out[0] = 0.0f;
}

// 256 threads/block, SPB=2 samples per block, FULLY unrolled:
// all scalar entry loads -> all 12 gather float4 (L2-resident tables) ->
// all 24 eps float4 (coalesced, nontemporal) -> compute.
// One flat dependence graph so VMEM issue is continuous; gather latency
// hides under the eps stream instead of serializing per sample.
template <bool USE_WS>
__global__ __launch_bounds__(256, 2) void ssvi_main(
    const int*   __restrict__ entries,  // [NSAMP, 3]
    const float* __restrict__ ys,       // [NSAMP]
    const float* __restrict__ eps,      // [3, NSAMP, K1, RANK]
    const float* __restrict__ means,    // [3, NCOL, RANK]
    const float* __restrict__ chols,    // [3, NCOL, RANK]
    float*       __restrict__ partial,  // [NBLK] (ws path)
    float*       __restrict__ out)      // scalar (atomic fallback path)
{
    const int t  = threadIdx.x;
    const int r4 = (t & 15) * 4;
    const int n0 = blockIdx.x * SPB;
    const size_t chunk = (size_t)K1 * RANK;   // 4096 floats per (d, n)

    // --- uniform entry columns: lowered to s_load, issue first ---
    int col[SPB][NDIM];
    #pragma unroll
    for (int i = 0; i < SPB; ++i)
        #pragma unroll
        for (int d = 0; d < NDIM; ++d)
            col[i][d] = entries[(n0 + i) * NDIM + d];

    // --- gather raw mean/chol quads for all samples (12 float4) ---
    f32x4 mq[SPB][NDIM], vq[SPB][NDIM];
    #pragma unroll
    for (int i = 0; i < SPB; ++i)
        #pragma unroll
        for (int d = 0; d < NDIM; ++d) {
            const size_t off = ((size_t)d * NCOL + col[i][d]) * RANK + r4;
            mq[i][d] = *(const f32x4*)(means + off);
            vq[i][d] = *(const f32x4*)(chols + off);
        }

    float yv[SPB];
    #pragma unroll
    for (int i = 0; i < SPB; ++i) yv[i] = ys[n0 + i];

    // --- issue ALL eps loads (SPB * 12 float4), coalesced & nontemporal ---
    f32x4 e[SPB][NDIM][4];
    #pragma unroll
    for (int i = 0; i < SPB; ++i) {
        const int n = n0 + i;
        const f32x4* e0p = (const f32x4*)(eps + ((size_t)0 * NSAMP + n) * chunk);
        const f32x4* e1p = (const f32x4*)(eps + ((size_t)1 * NSAMP + n) * chunk);
        const f32x4* e2p = (const f32x4*)(eps + ((size_t)2 * NSAMP + n) * chunk);
        #pragma unroll
        for (int it = 0; it < 4; ++it) {
            const int idx = it * 256 + t;
            e[i][0][it] = __builtin_nontemporal_load(e0p + idx);
            e[i][1][it] = __builtin_nontemporal_load(e1p + idx);
            e[i][2][it] = __builtin_nontemporal_load(e2p + idx);
        }
    }

    float acc = 0.0f;

    #pragma unroll
    for (int i = 0; i < SPB; ++i) {
        const f32x4 l0 = vq[i][0] * vq[i][0];   // S = L^2
        const f32x4 l1 = vq[i][1] * vq[i][1];
        const f32x4 l2 = vq[i][2] * vq[i][2];

        float pdf_acc = 0.0f;
        #pragma unroll
        for (int it = 0; it < 4; ++it) {
            const f32x4 f = (mq[i][0] + e[i][0][it] * l0)
                          * (mq[i][1] + e[i][1][it] * l1)
                          * (mq[i][2] + e[i][2][it] * l2);
            float part = (f[0] + f[1]) + (f[2] + f[3]);

            // reduce fs[n,k] over the 16 lanes sharing this k
            #pragma unroll
            for (int off = 8; off > 0; off >>= 1)
                part += __shfl_xor(part, off, 64);

            if ((t & 15) == 0) {
                const float d_ = part - yv[i];
                pdf_acc += d_ * d_;
            }
        }
        acc += pdf_acc * (0.5f / (float)K1);

        // KL: threads 0..47 cover (d = t>>4, r-quad) exactly once, from registers
        if (t < 48) {
            const int d = t >> 4;
            const f32x4 mm = (d == 0) ? mq[i][0] : (d == 1) ? mq[i][1] : mq[i][2];
            const f32x4 ll = (d == 0) ? l0 : (d == 1) ? l1 : l2;
            float klp = 0.0f;
            #pragma unroll
            for (int j = 0; j < 4; ++j)
                klp += 1.0f + 2.0f * __logf(ll[j]) - mm[j] * mm[j] - ll[j] * ll[j];
            acc += klp * (0.5f * LAMBD);
        }
    }

    // wave reduce then block reduce; one store (or atomic) per block
    #pragma unroll
    for (int off = 32; off > 0; off >>= 1)
        acc += __shfl_xor(acc, off, 64);
    __shared__ float wsum[4];
    if ((t & 63) == 0) wsum[t >> 6] = acc;
    __syncthreads();
    if (t == 0) {
        const float s = (wsum[0] + wsum[1]) + (wsum[2] + wsum[3]);
        if constexpr (USE_WS) partial[blockIdx.x] = s;
        else                  atomicAdd(out, s);
    }
}

__global__ __launch_bounds__(256) void ssvi_reduce(
    const float* __restrict__ partial, float* __restrict__ out)
{
    const int t = threadIdx.x;
    float v = 0.0f;
    #pragma unroll
    for (int i = 0; i < NBLK / 256; ++i)
        v += partial[i * 256 + t];
    #pragma unroll
    for (int off = 32; off > 0; off >>= 1)
        v += __shfl_xor(v, off, 64);
    __shared__ float wsum[4];
    if ((t & 63) == 0) wsum[t >> 6] = v;
    __syncthreads();
    if (t == 0) out[0] = (wsum[0] + wsum[1]) + (wsum[2] + wsum[3]);
}

extern "C" void kernel_launch(void* const* d_in, const int* in_sizes, int n_in,
                              void* d_out, int out_size, void* d_ws, size_t ws_size,
                              hipStream_t stream) {
    const int*   entries = (const int*)  d_in[0];
    const float* ys      = (const float*)d_in[1];
    const float* eps     = (const float*)d_in[2];
    const float* means   = (const float*)d_in[3];
    const float* chols   = (const float*)d_in[4];
    float* out = (float*)d_out;

    if (d_ws != nullptr && ws_size >= NBLK * sizeof(float)) {
        float* partial = (float*)d_ws;
        ssvi_main<true><<<NBLK, 256, 0, stream>>>(entries, ys, eps, means, chols, partial, out);
        ssvi_reduce<<<1, 256, 0, stream>>>(partial, out);
    } else {
        zero_out_kernel<<<1, 64, 0, stream>>>(out);
        ssvi_main<false><<<NBLK, 256, 0, stream>>>(entries, ys, eps, means, chols, nullptr, out);
    }
}